// Round 4
// baseline (213.161 us; speedup 1.0000x reference)
//
// r15 — break the phase convoy: dbuf act LDS + cross-tile software pipeline.
// r11-r14 post-mortem: dur pinned 66-74us across occupancy 47-70%, LDS
// traffic 2x, spills +-38MB. All pipes <=25%. Diagnosis: waves are
// CORRELATED — every block runs the same serial phase chain (stage->bar->
// L1->bar->store->bar->...), blocks stay lockstepped, each phase exposes
// full latency chip-wide. Fix (T14 / G15):
//  - act LDS double-buffered: layer reads buf[p], writes buf[p^1] -> the
//    intra-layer read/write barrier disappears: 6 -> 3 barriers per tile.
//  - persistent 2-tile blocks: X(t+1) issued to REGS at top of tile t
//    (~3 phases of cover), cvt+written to the free buffer DURING tile t's
//    L3+epilogue window -> stage leaves the critical path.
//  - rowany dbuf'd; zero in L2 window (2 barriers from readers+writers).
// Hazard trace (all barrier-separated):
//   L1 reads p / writes p^1  | p^1 last read by L2(t-1) [2 bars back],
//                              last big-write stage(t) in t-1 L3-win [1 bar]
//   L2 reads p^1 / writes p  | p last read by L1 [1 bar]
//   L3 reads p; stage(t+1) writes p^1 [L2 read it, 1 bar back]
//   rowany[p^1]: zeroed L2-win(t); OR-written L3-win(t); read L3-win(t+1)
// Gate: WRITE ~41MB, FETCH <=75MB (no spills), VGPR<=128 total.
// Predict: dur 66 -> 42-52us. If unchanged w/ clean gates: convoy theory
// falsified -> stage W via LDS next.
#include <hip/hip_runtime.h>

typedef __attribute__((ext_vector_type(8))) short short8;
typedef __attribute__((ext_vector_type(8))) unsigned short ushort8;
typedef __attribute__((ext_vector_type(4))) float f32x4;

#define MT 32            // batch rows per tile
#define TILES 2          // tiles per block (software pipeline depth)
#define STR 264          // bf16 elems per LDS row: 256 + 8 pad (528B, 16B-aligned)

__device__ __forceinline__ float bmax_r15() { return __uint_as_float(0x7F7F0000u); }

// plain RTNE fp32 -> bf16 bits (pre-epilogue values provably finite/small).
__device__ __forceinline__ unsigned short f2bf_r15(float f) {
    unsigned int u = __float_as_uint(f);
    return (unsigned short)((u + 0x7fffu + ((u >> 16) & 1u)) >> 16);
}

// pack: one thread per 64-lane fragment slot; gathers 8 k-elements and does
// ONE contiguous 16B write. Layout: dst[(frag*64+lane)*8 + j],
// frag=(n>>4)*8+(k>>5), lane=((k>>3)&3)*16+(n&15), j=k&7.
__global__ __launch_bounds__(256)
void pack_weights_r15(const float* __restrict__ W1,
                      const float* __restrict__ W2,
                      const float* __restrict__ W3,
                      unsigned short* __restrict__ ws) {
    int s = blockIdx.x * 256 + threadIdx.x;     // 80 x 256 = 20480 slots
    const float* src;
    unsigned short* dst;
    int N;
    if (s < 8192)       { src = W1; dst = ws;          N = 256; }
    else if (s < 16384) { src = W2; dst = ws + 65536;  N = 256; s -= 8192; }
    else                { src = W3; dst = ws + 131072; N = 128; s -= 16384; }
    int frag = s >> 6, lane = s & 63;
    int kb = (frag & 7) * 32 + (lane >> 4) * 8;   // k base (8 consecutive k)
    int n  = (frag >> 3) * 16 + (lane & 15);
    ushort8 o;
    #pragma unroll
    for (int j = 0; j < 8; ++j) o[j] = f2bf_r15(src[(kb + j) * N + n]);
    *(ushort8*)&dst[s * 8] = o;
}

// One 32x256 dense layer (K=256): MFMA reads from src buffer.
// Wave w owns col-tiles 4w..4w+3 and ALL 32 rows (2 row-tiles).
__device__ __forceinline__ void layer_mfma_r15(
    const unsigned short* __restrict__ src, const unsigned short* __restrict__ wp,
    int wave, int lane, int quad, int noff, f32x4 acc[2][4])
{
    #pragma unroll
    for (int k0 = 0; k0 < 8; ++k0) {
        short8 b[4];
        #pragma unroll
        for (int ct = 0; ct < 4; ++ct)
            b[ct] = *(const short8*)&wp[(((wave * 4 + ct) * 8 + k0) * 64 + lane) * 8];
        #pragma unroll
        for (int rt = 0; rt < 2; ++rt) {
            short8 a = *(const short8*)&src[(rt * 16 + noff) * STR + k0 * 32 + quad * 8];
            #pragma unroll
            for (int ct = 0; ct < 4; ++ct)
                acc[rt][ct] = __builtin_amdgcn_mfma_f32_16x16x32_bf16(a, b[ct], acc[rt][ct], 0, 0, 0);
        }
    }
}

// bias+relu+cvt, store to dst buffer (the OTHER one — no barrier needed
// between a layer's reads and its stores).
__device__ __forceinline__ void layer_store_r15(
    unsigned short* __restrict__ dst, const float* __restrict__ bias,
    int wave, int quad, int noff, f32x4 acc[2][4])
{
    #pragma unroll
    for (int ct = 0; ct < 4; ++ct) {
        int col = (wave * 4 + ct) * 16 + noff;
        float bv = bias[col];
        #pragma unroll
        for (int rt = 0; rt < 2; ++rt) {
            #pragma unroll
            for (int i = 0; i < 4; ++i) {
                float v = fmaxf(acc[rt][ct][i] + bv, 0.0f);   // relu; finite by data
                dst[(rt * 16 + quad * 4 + i) * STR + col] = f2bf_r15(v);
            }
        }
    }
}

// cvt prefetched fp32 regs -> bf16, write to act buffer (2048 float4/tile).
__device__ __forceinline__ void stage_from_regs_r15(
    unsigned short* __restrict__ dst, const float4* v, int tid)
{
    #pragma unroll
    for (int i = 0; i < 8; ++i) {
        int f = tid + i * 256;        // 64 float4-chunks per row
        int row = f >> 6;
        int c4 = f & 63;
        ushort4 p;
        p.x = f2bf_r15(v[i].x); p.y = f2bf_r15(v[i].y);
        p.z = f2bf_r15(v[i].z); p.w = f2bf_r15(v[i].w);
        *(ushort4*)&dst[row * STR + c4 * 4] = p;
    }
}

__global__ __launch_bounds__(256, 4)   // cap 128 regs; LDS 34KB -> 4 blocks/CU
void ColorNetwork_32495722561720_kernel(
        const float* __restrict__ obs,
        const int* __restrict__ amask,
        const float* __restrict__ b1,
        const float* __restrict__ b2,
        const float* __restrict__ b3,
        const unsigned short* __restrict__ w1p,
        const unsigned short* __restrict__ w2p,
        const unsigned short* __restrict__ w3p,
        float* __restrict__ out)
{
    // 2 x 16896 (act dbuf) + 256 (rowany dbuf) = 34048 B -> 4 blocks/CU
    __shared__ __align__(16) unsigned short act[2][MT * STR];
    __shared__ int rowany[2][MT];

    const int tid  = threadIdx.x;
    const int wave = tid >> 6;
    const int lane = tid & 63;
    const int quad = lane >> 4;
    const int noff = lane & 15;
    const size_t row0 = (size_t)blockIdx.x * (MT * TILES);

    if (tid < 2 * MT) ((int*)rowany)[tid] = 0;

    // ---- prologue: load X(t0) to regs, stage buf0, rowany0 ----
    float4 xf[8];
    {
        const float4* xin = (const float4*)(obs + row0 * 256);
        #pragma unroll
        for (int i = 0; i < 8; ++i) xf[i] = xin[tid + i * 256];
    }
    __syncthreads();   // rowany zeros visible before OR-writes
    stage_from_regs_r15(act[0], xf, tid);
    {
        const int4* min4 = (const int4*)(amask + row0 * 128);
        #pragma unroll
        for (int i = 0; i < 4; ++i) {
            int f = tid + i * 256;
            int4 m = min4[f];
            if (m.x | m.y | m.z | m.w) rowany[0][f >> 5] = 1;   // benign race, all write 1
        }
    }
    __syncthreads();   // buf0 + rowany0 ready

    int p = 0;
    #pragma unroll
    for (int t = 0; t < TILES; ++t, p ^= 1) {
        const size_t rowbase = row0 + (size_t)t * MT;
        const bool more = (t + 1 < TILES);

        // issue X(t+1) prefetch NOW — lands during this tile's 3 phases
        if (more) {
            const float4* xin = (const float4*)(obs + (rowbase + MT) * 256);
            #pragma unroll
            for (int i = 0; i < 8; ++i) xf[i] = xin[tid + i * 256];
        }

        {   // ---- layer 1: read act[p] -> write act[p^1] (single phase) ----
            f32x4 acc[2][4] = {};
            layer_mfma_r15(act[p], w1p, wave, lane, quad, noff, acc);
            layer_store_r15(act[p ^ 1], b1, wave, quad, noff, acc);
        }
        __syncthreads();

        // zero rowany[p^1] for t+1: 2 barriers from its t L3-win writers
        // and from its t-1 L3-win readers.
        if (more && tid < MT) rowany[p ^ 1][tid] = 0;

        {   // ---- layer 2: read act[p^1] -> write act[p] ----
            f32x4 acc[2][4] = {};
            layer_mfma_r15(act[p ^ 1], w2p, wave, lane, quad, noff, acc);
            layer_store_r15(act[p], b2, wave, quad, noff, acc);
        }
        __syncthreads();

        {   // ---- layer 3 (N=128): read act[p]; overlap stage(t+1)->act[p^1] ----
            f32x4 acc[2][2] = {};
            #pragma unroll
            for (int k0 = 0; k0 < 8; ++k0) {
                short8 b0 = *(const short8*)&w3p[(((wave * 2 + 0) * 8 + k0) * 64 + lane) * 8];
                short8 b1v = *(const short8*)&w3p[(((wave * 2 + 1) * 8 + k0) * 64 + lane) * 8];
                #pragma unroll
                for (int rt = 0; rt < 2; ++rt) {
                    short8 a = *(const short8*)&act[p][(rt * 16 + noff) * STR + k0 * 32 + quad * 8];
                    acc[rt][0] = __builtin_amdgcn_mfma_f32_16x16x32_bf16(a, b0, acc[rt][0], 0, 0, 0);
                    acc[rt][1] = __builtin_amdgcn_mfma_f32_16x16x32_bf16(a, b1v, acc[rt][1], 0, 0, 0);
                }
            }

            if (more) {   // hidden under L3 mfma + epilogue
                stage_from_regs_r15(act[p ^ 1], xf, tid);
                const int4* mn = (const int4*)(amask + (rowbase + MT) * 128);
                #pragma unroll
                for (int i = 0; i < 4; ++i) {
                    int f = tid + i * 256;
                    int4 m = mn[f];
                    if (m.x | m.y | m.z | m.w) rowany[p ^ 1][f >> 5] = 1;
                }
            }

            // epilogue: masked fp32 store (mask words L2-hot from rowany pass)
            const float BM = bmax_r15();
            #pragma unroll
            for (int ct = 0; ct < 2; ++ct) {
                int col = (wave * 2 + ct) * 16 + noff;
                float bv = b3[col];
                #pragma unroll
                for (int rt = 0; rt < 2; ++rt) {
                    #pragma unroll
                    for (int i = 0; i < 4; ++i) {
                        int row = rt * 16 + quad * 4 + i;
                        int m = amask[(rowbase + row) * 128 + col];
                        float v = acc[rt][ct][i] + bv;
                        v = fminf(fmaxf(v, -BM), BM);        // finite AND bf16-finite
                        if (!(v == v)) v = 0.0f;             // NaN scrub (paranoia)
                        if (!m) v = -BM;                     // FLOAT_MIN stand-in
                        if (!rowany[p][row]) v = (col == 0) ? 1.0f : -BM;
                        out[(rowbase + row) * 128 + col] = v;
                    }
                }
            }
        }
        __syncthreads();   // tile boundary: staged buf + rowany ready; L3 reads done
    }
}

extern "C" void kernel_launch(void* const* d_in, const int* in_sizes, int n_in,
                              void* d_out, int out_size, void* d_ws, size_t ws_size,
                              hipStream_t stream) {
    const float* obs   = (const float*)d_in[0];
    const int*   amask = (const int*)d_in[1];
    const float* W1 = (const float*)d_in[2];
    const float* b1 = (const float*)d_in[3];
    const float* W2 = (const float*)d_in[4];
    const float* b2 = (const float*)d_in[5];
    const float* W3 = (const float*)d_in[6];
    const float* b3 = (const float*)d_in[7];
    float* out = (float*)d_out;

    const int B = in_sizes[0] / 256;   // 65536 batch rows

    unsigned short* ws = (unsigned short*)d_ws;    // 163840 bf16 = 320 KB packed
    unsigned short* w1p = ws;
    unsigned short* w2p = ws + 65536;
    unsigned short* w3p = ws + 131072;

    pack_weights_r15<<<80, 256, 0, stream>>>(W1, W2, W3, ws);

    ColorNetwork_32495722561720_kernel<<<B / (MT * TILES), 256, 0, stream>>>(
        obs, amask, b1, b2, b3, w1p, w2p, w3p, out);
}